// Round 1
// 412.843 us; speedup vs baseline: 1.2506x; 1.2506x over previous
//
#include <hip/hip_runtime.h>
#include <cfloat>

// ClDiceLoss (B=2, C=1, 192^3) fp32 — register-streaming soft-skeletonize.
//
// Round-8: remove LDS staging entirely (prior kernel was ~90% LDS-pipe-bound:
// ~48 b128 wave-ops/512 cells ~= 52us + 34us bank conflicts ~= the 95us).
// New decomposition: W = 192 = 64 lanes x 3 cols -> ONE WAVE spans full x.
//   lane l owns cols 3l..3l+2; wave owns y-row gy; streams z with a 4-deep
//   register ring of x planes (5 rows gy-2..gy+2 per plane, halo rows re-read
//   from global = guaranteed L2 hits from neighbor strips).
//   M (7-pt cross min)  : x+-1 via 2 shfl/row, y+-1 in-register, z+-1 ring.
//   P (3x3x3 max of M)  : hx via 2 shfl/row, hxy in-register, z via 3-deep
//                         hxy shift register (h2,h1,h0).
//   out(z-2) = relu(x - relu(P - M)) emitted 2 planes behind the front.
// Boundaries: x edge == volume edge (full W in wave) -> cndmask pads
// (+inf for min / -inf for max); y edge -> -FLT_MAX row mask on M;
// z edge -> zlo/zhi guards on the hxy terms; clamped loads harmless (min dup).
// No __shared__, no __syncthreads: waves fully independent; per-wave
// reduction partials in last-iteration mode.

constexpr int D = 192, H = 192, W = 192, B = 2;
constexpr int HW = H * W;
constexpr int VOL = D * HW;
constexpr int CZ = 48;              // z-chunk (multiple of 4; divides D)
constexpr int NCH = D / CZ;         // 4 chunks
constexpr int WPB = 4;              // waves (y-strips) per block
constexpr int NGY = H / WPB;        // 48
constexpr int STEPS = CZ + 4;       // 52 pipeline steps (multiple of 4)
constexpr int NPART = B * NCH * H;  // 1536 per chain

__global__ __launch_bounds__(256, 3) void skel_iter(
    const float* __restrict__ srcA, float* __restrict__ dstA,
    const float* __restrict__ othA, double* __restrict__ partA,
    const float* __restrict__ srcB, float* __restrict__ dstB,
    const float* __restrict__ othB, double* __restrict__ partB,
    int last) {
  const int tid = threadIdx.x;
  const int lane = tid & 63;
  const int wv = tid >> 6;
  const int gy = blockIdx.x * WPB + wv;     // strip row 0..191
  const int chunk = blockIdx.y;             // 0..NCH-1
  const int b = blockIdx.z % B;
  const int chain = blockIdx.z / B;

  const float* __restrict__ vs = (chain ? srcB : srcA) + (size_t)b * VOL;
  float* __restrict__ vd = (chain ? dstB : dstA) + (size_t)b * VOL;
  const float* __restrict__ vo = (chain ? othB : othA) + (size_t)b * VOL;
  double* __restrict__ part = chain ? partB : partA;

  const int z0 = chunk * CZ;                // z0 % 4 == 0 (CZ mult of 4)
  const int c0 = 3 * lane;

  // Row byte-offsets (z-invariant), rows gy-2..gy+2 clamped (dup-harmless:
  // clamped rows feed only MIN terms; out-of-volume M rows masked below).
  int rb[5];
  #pragma unroll
  for (int r = 0; r < 5; ++r) rb[r] = min(max(gy - 2 + r, 0), H - 1) * W + c0;
  const bool ytop = (gy == 0), ybot = (gy == H - 1);
  const bool l0 = (lane == 0), l63 = (lane == 63);

  // Register state. All ring indices become compile-time constants via the
  // mod-4 phase unroll (z0%4==0 -> slot arithmetic depends only on p).
  float xa[4][5][3];     // x plane ring: plane q in slot q&3
  float Mprev[3];        // M(z-2), center row (for out)
  float h1[3], h2[3];    // hxy(z-2), hxy(z-3)
  float sp = 0.0f, ss = 0.0f;

  // Prologue: planes z0-2 -> slot 2, z0-1 -> slot 3 (clamped at z0==0).
  {
    const float* ps = vs + (size_t)max(z0 - 2, 0) * HW;
    #pragma unroll
    for (int r = 0; r < 5; ++r) {
      xa[2][r][0] = ps[rb[r]]; xa[2][r][1] = ps[rb[r] + 1]; xa[2][r][2] = ps[rb[r] + 2];
    }
    ps = vs + (size_t)max(z0 - 1, 0) * HW;
    #pragma unroll
    for (int r = 0; r < 5; ++r) {
      xa[3][r][0] = ps[rb[r]]; xa[3][r][1] = ps[rb[r] + 1]; xa[3][r][2] = ps[rb[r] + 2];
    }
  }

  #pragma unroll 1
  for (int s4 = 0; s4 < STEPS; s4 += 4) {
    #pragma unroll
    for (int p = 0; p < 4; ++p) {
      const int s = s4 + p;
      const int z = z0 - 1 + s;                  // pipeline front
      const int ld = p;                          // slot for plane z+1
      const int sm2 = (p + 1) & 3;               // plane z-2
      const int sm1 = (p + 2) & 3;               // plane z-1 (M center)
      const int sc = (p + 3) & 3;                // plane z

      // Issue next-plane loads early (consumed next step: full-step latency
      // slack; clamped dup at z edges is min-neutral).
      {
        const int zc = min(z + 1, D - 1);
        const float* ps = vs + (size_t)zc * HW;
        #pragma unroll
        for (int r = 0; r < 5; ++r) {
          xa[ld][r][0] = ps[rb[r]];
          xa[ld][r][1] = ps[rb[r] + 1];
          xa[ld][r][2] = ps[rb[r] + 2];
        }
      }

      const int zo = z - 2;
      const bool emit = (s >= 3) && (s <= CZ + 2);

      // Prefetch the weight row for the fused reduction (last iteration).
      float w0 = 0.f, w1 = 0.f, w2 = 0.f;
      if (last && emit) {
        const float* pvo = vo + (size_t)zo * HW + rb[2];
        w0 = pvo[0]; w1 = pvo[1]; w2 = pvo[2];
      }

      // ---- M(z-1): 7-pt cross min, rows gy-1..gy+1 (M rows 0..2) ----
      float xl[3], xr[3];
      #pragma unroll
      for (int r = 0; r < 3; ++r) {
        xl[r] = __shfl_up(xa[sm1][r + 1][2], 1, 64);    // col 3l-1
        xr[r] = __shfl_down(xa[sm1][r + 1][0], 1, 64);  // col 3l+3
        if (l0) xl[r] = FLT_MAX;    // x = -1  -> +inf pad (min-neutral)
        if (l63) xr[r] = FLT_MAX;   // x = 192 -> +inf pad
      }
      float Mc[3][3];
      #pragma unroll
      for (int r = 0; r < 3; ++r) {
        #pragma unroll
        for (int c = 0; c < 3; ++c) {
          const float le = (c == 0) ? xl[r] : xa[sm1][r + 1][c - 1];
          const float ri = (c == 2) ? xr[r] : xa[sm1][r + 1][c + 1];
          float v = fminf(xa[sm1][r + 1][c], fminf(le, ri));
          v = fminf(v, fminf(xa[sm1][r][c], xa[sm1][r + 2][c]));      // y+-1
          v = fminf(v, fminf(xa[sm2][r + 1][c], xa[sc][r + 1][c]));   // z+-1
          Mc[r][c] = v;
        }
      }
      // Out-of-volume M rows -> -inf (exact reduce_window -inf-pad for P).
      if (ytop) { Mc[0][0] = Mc[0][1] = Mc[0][2] = -FLT_MAX; }
      if (ybot) { Mc[2][0] = Mc[2][1] = Mc[2][2] = -FLT_MAX; }

      // ---- hxy(z-1): 3x3 in-plane max of M, collapsed over rows ----
      float ml[3], mr[3];
      #pragma unroll
      for (int r = 0; r < 3; ++r) {
        ml[r] = __shfl_up(Mc[r][2], 1, 64);
        mr[r] = __shfl_down(Mc[r][0], 1, 64);
        if (l0) ml[r] = -FLT_MAX;
        if (l63) mr[r] = -FLT_MAX;
      }
      float h0c[3];
      #pragma unroll
      for (int c = 0; c < 3; ++c) {
        float m = -FLT_MAX;
        #pragma unroll
        for (int r = 0; r < 3; ++r) {
          const float le = (c == 0) ? ml[r] : Mc[r][c - 1];
          const float ri = (c == 2) ? mr[r] : Mc[r][c + 1];
          m = fmaxf(m, fmaxf(fmaxf(le, ri), Mc[r][c]));
        }
        h0c[c] = m;
      }

      // ---- out(z-2) = relu(x - relu(P - M)) ----
      if (emit) {
        const bool zlo = (zo > 0), zhi = (zo < D - 1);
        float o[3];
        #pragma unroll
        for (int c = 0; c < 3; ++c) {
          float P = h1[c];
          if (zlo) P = fmaxf(P, h2[c]);
          if (zhi) P = fmaxf(P, h0c[c]);
          const float contour = fmaxf(P - Mprev[c], 0.0f);
          o[c] = fmaxf(xa[sm2][2][c] - contour, 0.0f);
        }
        if (last) {
          sp += o[0] * w0 + o[1] * w1 + o[2] * w2;
          ss += o[0] + o[1] + o[2];
        } else {
          float* pd = vd + (size_t)zo * HW + rb[2];
          pd[0] = o[0]; pd[1] = o[1]; pd[2] = o[2];
        }
      }

      // Ring advance (static names; compiler renames, no real movs survive).
      #pragma unroll
      for (int c = 0; c < 3; ++c) {
        h2[c] = h1[c];
        h1[c] = h0c[c];
        Mprev[c] = Mc[1][c];
      }
    }
  }

  if (last) {
    #pragma unroll
    for (int off = 32; off > 0; off >>= 1) {
      sp += __shfl_down(sp, off, 64);
      ss += __shfl_down(ss, off, 64);
    }
    if (lane == 0) {
      const int lin = (b * NCH + chunk) * H + gy;
      part[2 * lin] = (double)sp;
      part[2 * lin + 1] = (double)ss;
    }
  }
}

__global__ void finalize_kernel(const double* __restrict__ pa,
                                const double* __restrict__ pb,
                                float* __restrict__ out, int npart) {
  __shared__ double red[4][4];
  double s[4] = {0, 0, 0, 0};
  for (int i = threadIdx.x; i < npart; i += 256) {
    s[0] += pa[2 * i];
    s[1] += pa[2 * i + 1];
    s[2] += pb[2 * i];
    s[3] += pb[2 * i + 1];
  }
  #pragma unroll
  for (int off = 32; off > 0; off >>= 1)
    #pragma unroll
    for (int j = 0; j < 4; ++j) s[j] += __shfl_down(s[j], off, 64);
  const int wave = threadIdx.x >> 6, lane = threadIdx.x & 63;
  if (lane == 0)
    for (int j = 0; j < 4; ++j) red[j][wave] = s[j];
  __syncthreads();
  if (threadIdx.x == 0) {
    double t[4];
    for (int j = 0; j < 4; ++j)
      t[j] = red[j][0] + red[j][1] + red[j][2] + red[j][3];
    const double recall = (t[0] + 1e-12) / (t[1] + 1e-12);
    const double accv = (t[2] + 1e-12) / (t[3] + 1e-12);
    const double cldice = 2.0 * recall * accv / (recall + accv);
    out[0] = (float)(1.0 - cldice);
  }
}

extern "C" void kernel_launch(void* const* d_in, const int* in_sizes, int n_in,
                              void* d_out, int out_size, void* d_ws, size_t ws_size,
                              hipStream_t stream) {
  const float* pred = (const float*)d_in[0];
  const float* target = (const float*)d_in[1];
  float* out = (float*)d_out;
  const size_t NT = (size_t)VOL * B;

  const dim3 blk(256, 1, 1);
  const size_t need_merged = 4 * NT * sizeof(float) + 4 * NPART * sizeof(double);

  if (ws_size >= need_merged) {
    float* a0 = (float*)d_ws;
    float* a1 = a0 + NT;
    float* c0 = a1 + NT;
    float* c1 = c0 + NT;
    double* pA = (double*)(c1 + NT);
    double* pB = pA + 2 * NPART;
    const dim3 grd(NGY, NCH, 2 * B);   // 768 blocks = exactly 3/CU
    skel_iter<<<grd, blk, 0, stream>>>(target, a0, pred, pA, pred, c0, target, pB, 0);
    skel_iter<<<grd, blk, 0, stream>>>(a0, a1, pred, pA, c0, c1, target, pB, 0);
    skel_iter<<<grd, blk, 0, stream>>>(a1, a0, pred, pA, c1, c0, target, pB, 0);
    skel_iter<<<grd, blk, 0, stream>>>(a0, a1, pred, pA, c0, c1, target, pB, 0);
    skel_iter<<<grd, blk, 0, stream>>>(a1, a0, pred, pA, c1, c0, target, pB, 1);
    finalize_kernel<<<1, 256, 0, stream>>>(pA, pB, out, NPART);
  } else {
    float* b0 = (float*)d_ws;
    float* b1 = b0 + NT;
    double* pA = (double*)(b1 + NT);
    double* pB = pA + 2 * NPART;
    const dim3 grd(NGY, NCH, B);       // chain = 0 only
    skel_iter<<<grd, blk, 0, stream>>>(target, b0, pred, pA, nullptr, nullptr, nullptr, nullptr, 0);
    skel_iter<<<grd, blk, 0, stream>>>(b0, b1, pred, pA, nullptr, nullptr, nullptr, nullptr, 0);
    skel_iter<<<grd, blk, 0, stream>>>(b1, b0, pred, pA, nullptr, nullptr, nullptr, nullptr, 0);
    skel_iter<<<grd, blk, 0, stream>>>(b0, b1, pred, pA, nullptr, nullptr, nullptr, nullptr, 0);
    skel_iter<<<grd, blk, 0, stream>>>(b1, b0, pred, pA, nullptr, nullptr, nullptr, nullptr, 1);
    skel_iter<<<grd, blk, 0, stream>>>(pred, b0, target, pB, nullptr, nullptr, nullptr, nullptr, 0);
    skel_iter<<<grd, blk, 0, stream>>>(b0, b1, target, pB, nullptr, nullptr, nullptr, nullptr, 0);
    skel_iter<<<grd, blk, 0, stream>>>(b1, b0, target, pB, nullptr, nullptr, nullptr, nullptr, 0);
    skel_iter<<<grd, blk, 0, stream>>>(b0, b1, target, pB, nullptr, nullptr, nullptr, nullptr, 0);
    skel_iter<<<grd, blk, 0, stream>>>(b1, b0, target, pB, nullptr, nullptr, nullptr, nullptr, 1);
    finalize_kernel<<<1, 256, 0, stream>>>(pA, pB, out, NPART);
  }
}